// Round 9
// baseline (142.691 us; speedup 1.0000x reference)
//
#include <hip/hip_runtime.h>
#include <hip/hip_bf16.h>

typedef __bf16 bf16x8 __attribute__((ext_vector_type(8)));
typedef float f32x4 __attribute__((ext_vector_type(4)));
typedef int   i32x4 __attribute__((ext_vector_type(4)));

#define NB 8
#define NT 2048
#define NC 1024
#define NH 64

__device__ __forceinline__ unsigned short bfbits(float f) {
    return __builtin_bit_cast(unsigned short, (__bf16)f);
}

__device__ __forceinline__ void gload(f32x4& d, const void* p) {
    asm volatile("global_load_dwordx4 %0, %1, off" : "=v"(d) : "v"(p));
}
__device__ __forceinline__ void gloadi(i32x4& d, const void* p) {
    asm volatile("global_load_dwordx4 %0, %1, off" : "=v"(d) : "v"(p));
}

// ---------------- kernel 1: W -> W^T (bf16) ----------------
__global__ __launch_bounds__(256) void wt_kernel(const float* __restrict__ Wq,
                                                 const float* __restrict__ Wk,
                                                 const float* __restrict__ Wv,
                                                 unsigned short* __restrict__ Wt) {
    int idx = blockIdx.x * 256 + threadIdx.x;
    int n = idx >> 16;
    int r = idx & 65535;
    int c = r >> 6;
    int h = r & 63;
    const float* W = (n == 0) ? Wq : ((n == 1) ? Wk : Wv);
    float x = W[c * 64 + h];
    Wt[(n << 16) + h * 1024 + c] = bfbits(x);
}

// ---------------- kernel 2: asm-pipelined streaming QKV projection ----------------
// One wave per 16-row tile, split-K=2, no LDS/barriers. Inline-asm VMEM loads
// with a 3-deep static pipeline and counted vmcnt: 18 loads (18KB) per wave
// permanently in flight — the compiler cannot serialize register liveness.
__global__ __launch_bounds__(256, 4) void proj_kernel(const float* __restrict__ Xv,
                                                      const float* __restrict__ Xk,
                                                      const float* __restrict__ Xq,
                                                      const unsigned short* __restrict__ Wt,
                                                      float* __restrict__ P) {
    int wid  = blockIdx.x * 4 + (threadIdx.x >> 6);   // 0..6143
    int lane = threadIdx.x & 63;
    int slice = wid & 1;
    int rest  = wid >> 1;
    int type = rest >> 10;         // 0=Q,1=K,2=V
    int tile = rest & 1023;
    int row0 = tile << 4;
    const float* X = (type == 0) ? Xq : ((type == 1) ? Xk : Xv);
    const unsigned short* W = Wt + (type << 16);
    int lo = lane & 15, hi = lane >> 4;

    const char* xb_ = (const char*)(X + (size_t)(row0 + lo) * NC + hi * 8) + (slice << 11);
    const char* wb_ = (const char*)(W + lo * 1024 + hi * 8) + (slice << 10);

    f32x4 XA[3], XB[3];
    i32x4 WR[3][4];
    f32x4 acc[4];
#pragma unroll
    for (int ct = 0; ct < 4; ++ct) acc[ct] = 0.f;

#define ISSUE(s, sl)                                          \
    do {                                                      \
        gload(XA[sl], xb_ + (s) * 128);                       \
        gload(XB[sl], xb_ + (s) * 128 + 16);                  \
        gloadi(WR[sl][0], wb_ + (s) * 64);                    \
        gloadi(WR[sl][1], wb_ + (s) * 64 + 32768);            \
        gloadi(WR[sl][2], wb_ + (s) * 64 + 65536);            \
        gloadi(WR[sl][3], wb_ + (s) * 64 + 98304);            \
    } while (0)

    ISSUE(0, 0);
    ISSUE(1, 1);
    ISSUE(2, 2);

#pragma unroll
    for (int s = 0; s < 16; ++s) {
        const int sl = s % 3;
        if (s <= 13)      asm volatile("s_waitcnt vmcnt(12)" ::: "memory");
        else if (s == 14) asm volatile("s_waitcnt vmcnt(6)" ::: "memory");
        else              asm volatile("s_waitcnt vmcnt(0)" ::: "memory");
        __builtin_amdgcn_sched_barrier(0);
        bf16x8 av;
        av[0] = (__bf16)XA[sl][0]; av[1] = (__bf16)XA[sl][1];
        av[2] = (__bf16)XA[sl][2]; av[3] = (__bf16)XA[sl][3];
        av[4] = (__bf16)XB[sl][0]; av[5] = (__bf16)XB[sl][1];
        av[6] = (__bf16)XB[sl][2]; av[7] = (__bf16)XB[sl][3];
#pragma unroll
        for (int ct = 0; ct < 4; ++ct) {
            bf16x8 bv = __builtin_bit_cast(bf16x8, WR[sl][ct]);
            acc[ct] = __builtin_amdgcn_mfma_f32_16x16x32_bf16(av, bv, acc[ct], 0, 0, 0);
        }
        if (s + 3 < 16) {
            const int s3 = s + 3;
            const int sl3 = s3 % 3;
            ISSUE(s3, sl3);
        }
    }
#undef ISSUE

    // ---- write fp32 partials ----
    float* Ps = P + (size_t)slice * 3145728 + (size_t)type * 1048576;
    if (type < 2) {
#pragma unroll
        for (int ct = 0; ct < 4; ++ct)
#pragma unroll
            for (int r = 0; r < 4; ++r) {
                int row = row0 + hi * 4 + r;
                int h = lo + 16 * ct;
                Ps[(size_t)row * NH + h] = acc[ct][r];
            }
    } else {
        int b = row0 >> 11;
        int t = (row0 & 2047) + hi * 4;
#pragma unroll
        for (int ct = 0; ct < 4; ++ct) {
            int h = lo + 16 * ct;
            *(float4*)(Ps + (size_t)(b * NH + h) * NT + t) =
                make_float4(acc[ct][0], acc[ct][1], acc[ct][2], acc[ct][3]);
        }
    }
}

// ---------------- kernel 2b: combine split-K partials -> bf16 ----------------
__global__ __launch_bounds__(256) void combine_kernel(const float* __restrict__ P,
                                                      unsigned short* __restrict__ OUT) {
    int i = blockIdx.x * 256 + threadIdx.x;
    float4 a = *(const float4*)(P + 4 * (size_t)i);
    float4 c = *(const float4*)(P + 3145728 + 4 * (size_t)i);
    ushort4 o;
    o.x = bfbits(a.x + c.x);
    o.y = bfbits(a.y + c.y);
    o.z = bfbits(a.z + c.z);
    o.w = bfbits(a.w + c.w);
    *(ushort4*)(OUT + 4 * (size_t)i) = o;
}

// ---------------- kernel 3: causal flash attention (MFMA) ----------------
__global__ __launch_bounds__(256) void attn_kernel(const unsigned short* __restrict__ Q,
                                                   const unsigned short* __restrict__ K,
                                                   const unsigned short* __restrict__ VT,
                                                   float* __restrict__ out) {
    __shared__ __align__(16) unsigned short p_lds[4 * 512];
    __shared__ __align__(16) float acc_lds[4 * 16 * 64];
    __shared__ float m_lds[4][16];
    __shared__ float l_lds[4][16];

    int b  = blockIdx.x >> 7;
    int qt = blockIdx.x & 127;
    int q0 = qt << 4;
    int w    = threadIdx.x >> 6;
    int lane = threadIdx.x & 63;
    int lo = lane & 15, hi = lane >> 4;

    const unsigned short* qb = Q + (size_t)(b * NT + q0 + lo) * NH + hi * 8;
    bf16x8 qf0 = *(const bf16x8*)(qb);
    bf16x8 qf1 = *(const bf16x8*)(qb + 32);

    int Ctot = (q0 + 16 + 31) >> 5;
    int c0 = (Ctot * w) >> 2;
    int c1 = (Ctot * (w + 1)) >> 2;

    float m[4], l[4];
    f32x4 acc[4];
#pragma unroll
    for (int r = 0; r < 4; ++r) { m[r] = -1e30f; l[r] = 0.f; }
#pragma unroll
    for (int ct = 0; ct < 4; ++ct) acc[ct] = 0.f;

    const float SC = 0.03125f * 1.44269504088896340736f;
    unsigned short* pl = p_lds + w * 512;

    for (int c = c0; c < c1; ++c) {
        int s0 = c << 5;
        const unsigned short* kb = K + (size_t)(b * NT + s0 + lo) * NH + hi * 8;
        f32x4 S0 = 0.f, S1 = 0.f;
        S0 = __builtin_amdgcn_mfma_f32_16x16x32_bf16(qf0, *(const bf16x8*)(kb), S0, 0, 0, 0);
        S0 = __builtin_amdgcn_mfma_f32_16x16x32_bf16(qf1, *(const bf16x8*)(kb + 32), S0, 0, 0, 0);
        S1 = __builtin_amdgcn_mfma_f32_16x16x32_bf16(qf0, *(const bf16x8*)(kb + 16 * NH), S1, 0, 0, 0);
        S1 = __builtin_amdgcn_mfma_f32_16x16x32_bf16(qf1, *(const bf16x8*)(kb + 16 * NH + 32), S1, 0, 0, 0);

        int s_a = s0 + lo, s_b = s0 + 16 + lo;
        float z0[4], z1[4], mt[4];
#pragma unroll
        for (int r = 0; r < 4; ++r) {
            int qi = q0 + hi * 4 + r;
            z0[r] = (s_a <= qi) ? S0[r] * SC : -1e30f;
            z1[r] = (s_b <= qi) ? S1[r] * SC : -1e30f;
            mt[r] = fmaxf(z0[r], z1[r]);
        }
#pragma unroll
        for (int d = 1; d < 16; d <<= 1)
#pragma unroll
            for (int r = 0; r < 4; ++r)
                mt[r] = fmaxf(mt[r], __shfl_xor(mt[r], d, 16));

        float p0[4], p1[4], rs[4];
#pragma unroll
        for (int r = 0; r < 4; ++r) {
            float mn = fmaxf(m[r], mt[r]);
            float al = exp2f(m[r] - mn);
            int qi = q0 + hi * 4 + r;
            p0[r] = (s_a <= qi) ? exp2f(z0[r] - mn) : 0.f;
            p1[r] = (s_b <= qi) ? exp2f(z1[r] - mn) : 0.f;
            rs[r] = p0[r] + p1[r];
            m[r] = mn;
            l[r] *= al;
            acc[0][r] *= al; acc[1][r] *= al; acc[2][r] *= al; acc[3][r] *= al;
        }
#pragma unroll
        for (int d = 1; d < 16; d <<= 1)
#pragma unroll
            for (int r = 0; r < 4; ++r)
                rs[r] += __shfl_xor(rs[r], d, 16);
#pragma unroll
        for (int r = 0; r < 4; ++r) {
            l[r] += rs[r];
            int ql = hi * 4 + r;
            pl[ql * 32 + lo]      = bfbits(p0[r]);
            pl[ql * 32 + 16 + lo] = bfbits(p1[r]);
        }
        bf16x8 pa = *(const bf16x8*)(pl + lo * 32 + hi * 8);
        const unsigned short* vb = VT + (size_t)(b * NH + lo) * NT + s0 + hi * 8;
#pragma unroll
        for (int ct = 0; ct < 4; ++ct) {
            bf16x8 vv = *(const bf16x8*)(vb + ct * 16 * NT);
            acc[ct] = __builtin_amdgcn_mfma_f32_16x16x32_bf16(pa, vv, acc[ct], 0, 0, 0);
        }
    }

#pragma unroll
    for (int r = 0; r < 4; ++r) {
        int ql = hi * 4 + r;
#pragma unroll
        for (int ct = 0; ct < 4; ++ct)
            acc_lds[(w * 16 + ql) * 64 + lo + 16 * ct] = acc[ct][r];
    }
    if (lo == 0) {
#pragma unroll
        for (int r = 0; r < 4; ++r) {
            m_lds[w][hi * 4 + r] = m[r];
            l_lds[w][hi * 4 + r] = l[r];
        }
    }
    __syncthreads();

    int q  = threadIdx.x >> 4;
    int h0 = (threadIdx.x & 15) << 2;
    float M = fmaxf(fmaxf(m_lds[0][q], m_lds[1][q]), fmaxf(m_lds[2][q], m_lds[3][q]));
    float L = 0.f;
    float ox = 0.f, oy = 0.f, oz = 0.f, ow = 0.f;
#pragma unroll
    for (int ww = 0; ww < 4; ++ww) {
        float a_ = exp2f(m_lds[ww][q] - M);
        L += a_ * l_lds[ww][q];
        const float* p = acc_lds + (ww * 16 + q) * 64 + h0;
        ox += a_ * p[0]; oy += a_ * p[1]; oz += a_ * p[2]; ow += a_ * p[3];
    }
    float inv = 1.0f / L;
    float4 res = make_float4(ox * inv, oy * inv, oz * inv, ow * inv);
    *(float4*)(out + (size_t)(b * NT + q0 + q) * NH + h0) = res;
}

extern "C" void kernel_launch(void* const* d_in, const int* in_sizes, int n_in,
                              void* d_out, int out_size, void* d_ws, size_t ws_size,
                              hipStream_t stream) {
    const float* values  = (const float*)d_in[0];
    const float* keys    = (const float*)d_in[1];
    const float* queries = (const float*)d_in[2];
    const float* Wk = (const float*)d_in[3];
    const float* Wq = (const float*)d_in[4];
    const float* Wv = (const float*)d_in[5];
    float* out = (float*)d_out;

    unsigned short* Wt = (unsigned short*)d_ws;        // 196608 ushorts
    unsigned short* Qb = Wt + 196608;                  // Q,K,VT: 3x1048576 ushorts
    unsigned short* Kb = Qb + 1048576;
    unsigned short* VT = Kb + 1048576;
    float* P = (float*)(VT + 1048576);                 // 2 x 3145728 fp32 partials

    wt_kernel<<<768, 256, 0, stream>>>(Wq, Wk, Wv, Wt);
    proj_kernel<<<1536, 256, 0, stream>>>(values, keys, queries, Wt, P);
    combine_kernel<<<3072, 256, 0, stream>>>(P, Qb);
    attn_kernel<<<1024, 256, 0, stream>>>(Qb, Kb, VT, out);
}

// Round 10
// 114.796 us; speedup vs baseline: 1.2430x; 1.2430x over previous
//
#include <hip/hip_runtime.h>
#include <hip/hip_bf16.h>

typedef __bf16 bf16x8 __attribute__((ext_vector_type(8)));
typedef float f32x4 __attribute__((ext_vector_type(4)));

#define NB 8
#define NT 2048
#define NC 1024
#define NH 64

__device__ __forceinline__ unsigned short bfbits(float f) {
    return __builtin_bit_cast(unsigned short, (__bf16)f);
}

__device__ __forceinline__ void gl_lds16(const void* g, void* l) {
    __builtin_amdgcn_global_load_lds(
        (const __attribute__((address_space(1))) void*)g,
        (__attribute__((address_space(3))) void*)l, 16, 0, 0);
}

// ---------------- kernel 1: W -> frag-major bf16 ----------------
// Wt2 layout: [3][128 kblk][64 h][8 k] bf16  (B-frag = 16 contiguous lanes x 16B)
__global__ __launch_bounds__(256) void wt_kernel(const float* __restrict__ Wq,
                                                 const float* __restrict__ Wk,
                                                 const float* __restrict__ Wv,
                                                 unsigned short* __restrict__ Wt2) {
    int idx = blockIdx.x * 256 + threadIdx.x;   // 0 .. 196607
    int n = idx >> 16;
    int r = idx & 65535;
    int kblk = r >> 9;
    int rest = r & 511;
    int j8 = rest >> 6;
    int h = rest & 63;          // fastest -> coalesced source reads
    const float* W = (n == 0) ? Wq : ((n == 1) ? Wk : Wv);
    float x = W[(kblk * 8 + j8) * 64 + h];
    Wt2[(n << 16) + kblk * 512 + h * 8 + j8] = bfbits(x);
}

// ---------------- kernel 2: sequential-stream QKV projection ----------------
// block = 4 waves, 16 rows x FULL K=1024 staged to LDS (64KB fp32).
// Each wave stages 4 whole contiguous 4KB rows (16 x 1KB global_load_lds,
// sequential addresses -> DRAM row-buffer streaming). In-block split-K=4:
// wave w computes k in [w*256,(w+1)*256); LDS reduction combines.
// In-row XOR swizzle (byte ^ (row&7)<<4) applied on pre-swizzled SOURCE and
// on A-frag reads -> conflict-free despite 4KB row stride.
__global__ __launch_bounds__(256, 2) void proj_kernel(const float* __restrict__ Xv,
                                                      const float* __restrict__ Xk,
                                                      const float* __restrict__ Xq,
                                                      const unsigned short* __restrict__ Wt2,
                                                      unsigned short* __restrict__ Q,
                                                      unsigned short* __restrict__ K,
                                                      unsigned short* __restrict__ VT) {
    __shared__ __align__(16) char Xs[16 * 4096];     // 64KB: [16 rows][4KB]
    __shared__ __align__(16) float Pacc[4][16][64];  // 16KB

    int type = blockIdx.x >> 10;         // 0=Q,1=K,2=V
    int tile = blockIdx.x & 1023;        // 16-row tiles over 16384 rows
    int row0 = tile << 4;
    const float* X = (type == 0) ? Xq : ((type == 1) ? Xk : Xv);
    const unsigned short* W2 = Wt2 + (type << 16);

    int tid  = threadIdx.x;
    int w    = tid >> 6;
    int lane = tid & 63;
    int lo = lane & 15, hi = lane >> 4;

    // ---- stage: wave w loads rows w*4 .. w*4+3, each as 4 x 1KB sequential ----
    const char* Xg = (const char*)X + (size_t)row0 * 4096;
#pragma unroll
    for (int j = 0; j < 4; ++j) {
        int r = w * 4 + j;
        int sw = (r & 7) << 4;
        const char* src = Xg + (size_t)r * 4096 + ((lane * 16) ^ sw);
        char* dst = Xs + r * 4096;          // wave-uniform base (+lane*16 by HW)
#pragma unroll
        for (int i = 0; i < 4; ++i)
            gl_lds16(src + i * 1024, dst + i * 1024);
    }
    asm volatile("s_waitcnt vmcnt(0)" ::: "memory");
    __builtin_amdgcn_s_barrier();

    // ---- compute: wave w owns k in [w*256, (w+1)*256) ----
    f32x4 acc[4];
#pragma unroll
    for (int ct = 0; ct < 4; ++ct) acc[ct] = 0.f;
    const char* xrow = Xs + lo * 4096;
    int sw = (lo & 7) << 4;
#pragma unroll
    for (int ks = 0; ks < 8; ++ks) {
        int cb = w * 1024 + ks * 128 + hi * 32;     // byte col within row
        f32x4 a0 = *(const f32x4*)(xrow + (cb ^ sw));
        f32x4 a1 = *(const f32x4*)(xrow + ((cb + 16) ^ sw));
        bf16x8 af;
        af[0] = (__bf16)a0[0]; af[1] = (__bf16)a0[1]; af[2] = (__bf16)a0[2]; af[3] = (__bf16)a0[3];
        af[4] = (__bf16)a1[0]; af[5] = (__bf16)a1[1]; af[6] = (__bf16)a1[2]; af[7] = (__bf16)a1[3];
        int kb = (w * 8 + ks) * 4 + hi;             // kblk index
#pragma unroll
        for (int ct = 0; ct < 4; ++ct) {
            bf16x8 bf = *(const bf16x8*)(W2 + ((kb * 64) + ct * 16 + lo) * 8);
            acc[ct] = __builtin_amdgcn_mfma_f32_16x16x32_bf16(af, bf, acc[ct], 0, 0, 0);
        }
    }

    // ---- in-block split-K reduction via LDS ----
#pragma unroll
    for (int ct = 0; ct < 4; ++ct)
#pragma unroll
        for (int r = 0; r < 4; ++r)
            Pacc[w][hi * 4 + r][ct * 16 + lo] = acc[ct][r];
    __syncthreads();

    if (type < 2) {
        unsigned short* O = (type == 0) ? Q : K;
        int row = tid >> 4;
        int hg = tid & 15;
        f32x4 s = *(const f32x4*)&Pacc[0][row][hg * 4];
#pragma unroll
        for (int w4 = 1; w4 < 4; ++w4) {
            f32x4 p = *(const f32x4*)&Pacc[w4][row][hg * 4];
            s[0] += p[0]; s[1] += p[1]; s[2] += p[2]; s[3] += p[3];
        }
        ushort4 o;
        o.x = bfbits(s[0]); o.y = bfbits(s[1]); o.z = bfbits(s[2]); o.w = bfbits(s[3]);
        *(ushort4*)(O + (size_t)(row0 + row) * NH + hg * 4) = o;
    } else {
        int h = tid >> 2;
        int rg = tid & 3;
        int b = row0 >> 11;
        int t0 = row0 & 2047;
        float s[4];
#pragma unroll
        for (int j = 0; j < 4; ++j) {
            s[j] = Pacc[0][rg * 4 + j][h] + Pacc[1][rg * 4 + j][h]
                 + Pacc[2][rg * 4 + j][h] + Pacc[3][rg * 4 + j][h];
        }
        ushort4 o;
        o.x = bfbits(s[0]); o.y = bfbits(s[1]); o.z = bfbits(s[2]); o.w = bfbits(s[3]);
        *(ushort4*)(VT + (size_t)(b * NH + h) * NT + t0 + rg * 4) = o;
    }
}

// ---------------- kernel 3: causal flash attention (MFMA) ----------------
// block = 4 waves, one 16-row Q-tile, 4-way split of the s-range + LDS merge
__global__ __launch_bounds__(256) void attn_kernel(const unsigned short* __restrict__ Q,
                                                   const unsigned short* __restrict__ K,
                                                   const unsigned short* __restrict__ VT,
                                                   float* __restrict__ out) {
    __shared__ __align__(16) unsigned short p_lds[4 * 512];
    __shared__ __align__(16) float acc_lds[4 * 16 * 64];
    __shared__ float m_lds[4][16];
    __shared__ float l_lds[4][16];

    int b  = blockIdx.x >> 7;
    int qt = blockIdx.x & 127;
    int q0 = qt << 4;
    int w    = threadIdx.x >> 6;
    int lane = threadIdx.x & 63;
    int lo = lane & 15, hi = lane >> 4;

    const unsigned short* qb = Q + (size_t)(b * NT + q0 + lo) * NH + hi * 8;
    bf16x8 qf0 = *(const bf16x8*)(qb);
    bf16x8 qf1 = *(const bf16x8*)(qb + 32);

    int Ctot = (q0 + 16 + 31) >> 5;
    int c0 = (Ctot * w) >> 2;
    int c1 = (Ctot * (w + 1)) >> 2;

    float m[4], l[4];
    f32x4 acc[4];
#pragma unroll
    for (int r = 0; r < 4; ++r) { m[r] = -1e30f; l[r] = 0.f; }
#pragma unroll
    for (int ct = 0; ct < 4; ++ct) acc[ct] = 0.f;

    const float SC = 0.03125f * 1.44269504088896340736f;
    unsigned short* pl = p_lds + w * 512;

    for (int c = c0; c < c1; ++c) {
        int s0 = c << 5;
        const unsigned short* kb = K + (size_t)(b * NT + s0 + lo) * NH + hi * 8;
        f32x4 S0 = 0.f, S1 = 0.f;
        S0 = __builtin_amdgcn_mfma_f32_16x16x32_bf16(qf0, *(const bf16x8*)(kb), S0, 0, 0, 0);
        S0 = __builtin_amdgcn_mfma_f32_16x16x32_bf16(qf1, *(const bf16x8*)(kb + 32), S0, 0, 0, 0);
        S1 = __builtin_amdgcn_mfma_f32_16x16x32_bf16(qf0, *(const bf16x8*)(kb + 16 * NH), S1, 0, 0, 0);
        S1 = __builtin_amdgcn_mfma_f32_16x16x32_bf16(qf1, *(const bf16x8*)(kb + 16 * NH + 32), S1, 0, 0, 0);

        int s_a = s0 + lo, s_b = s0 + 16 + lo;
        float z0[4], z1[4], mt[4];
#pragma unroll
        for (int r = 0; r < 4; ++r) {
            int qi = q0 + hi * 4 + r;
            z0[r] = (s_a <= qi) ? S0[r] * SC : -1e30f;
            z1[r] = (s_b <= qi) ? S1[r] * SC : -1e30f;
            mt[r] = fmaxf(z0[r], z1[r]);
        }
#pragma unroll
        for (int d = 1; d < 16; d <<= 1)
#pragma unroll
            for (int r = 0; r < 4; ++r)
                mt[r] = fmaxf(mt[r], __shfl_xor(mt[r], d, 16));

        float p0[4], p1[4], rs[4];
#pragma unroll
        for (int r = 0; r < 4; ++r) {
            float mn = fmaxf(m[r], mt[r]);
            float al = exp2f(m[r] - mn);
            int qi = q0 + hi * 4 + r;
            p0[r] = (s_a <= qi) ? exp2f(z0[r] - mn) : 0.f;
            p1[r] = (s_b <= qi) ? exp2f(z1[r] - mn) : 0.f;
            rs[r] = p0[r] + p1[r];
            m[r] = mn;
            l[r] *= al;
            acc[0][r] *= al; acc[1][r] *= al; acc[2][r] *= al; acc[3][r] *= al;
        }
#pragma unroll
        for (int d = 1; d < 16; d <<= 1)
#pragma unroll
            for (int r = 0; r < 4; ++r)
                rs[r] += __shfl_xor(rs[r], d, 16);
#pragma unroll
        for (int r = 0; r < 4; ++r) {
            l[r] += rs[r];
            int ql = hi * 4 + r;
            pl[ql * 32 + lo]      = bfbits(p0[r]);
            pl[ql * 32 + 16 + lo] = bfbits(p1[r]);
        }
        bf16x8 pa = *(const bf16x8*)(pl + lo * 32 + hi * 8);
        const unsigned short* vb = VT + (size_t)(b * NH + lo) * NT + s0 + hi * 8;
#pragma unroll
        for (int ct = 0; ct < 4; ++ct) {
            bf16x8 vv = *(const bf16x8*)(vb + ct * 16 * NT);
            acc[ct] = __builtin_amdgcn_mfma_f32_16x16x32_bf16(pa, vv, acc[ct], 0, 0, 0);
        }
    }

#pragma unroll
    for (int r = 0; r < 4; ++r) {
        int ql = hi * 4 + r;
#pragma unroll
        for (int ct = 0; ct < 4; ++ct)
            acc_lds[(w * 16 + ql) * 64 + lo + 16 * ct] = acc[ct][r];
    }
    if (lo == 0) {
#pragma unroll
        for (int r = 0; r < 4; ++r) {
            m_lds[w][hi * 4 + r] = m[r];
            l_lds[w][hi * 4 + r] = l[r];
        }
    }
    __syncthreads();

    int q  = threadIdx.x >> 4;
    int h0 = (threadIdx.x & 15) << 2;
    float M = fmaxf(fmaxf(m_lds[0][q], m_lds[1][q]), fmaxf(m_lds[2][q], m_lds[3][q]));
    float L = 0.f;
    float ox = 0.f, oy = 0.f, oz = 0.f, ow = 0.f;
#pragma unroll
    for (int ww = 0; ww < 4; ++ww) {
        float a_ = exp2f(m_lds[ww][q] - M);
        L += a_ * l_lds[ww][q];
        const float* p = acc_lds + (ww * 16 + q) * 64 + h0;
        ox += a_ * p[0]; oy += a_ * p[1]; oz += a_ * p[2]; ow += a_ * p[3];
    }
    float inv = 1.0f / L;
    float4 res = make_float4(ox * inv, oy * inv, oz * inv, ow * inv);
    *(float4*)(out + (size_t)(b * NT + q0 + q) * NH + h0) = res;
}

extern "C" void kernel_launch(void* const* d_in, const int* in_sizes, int n_in,
                              void* d_out, int out_size, void* d_ws, size_t ws_size,
                              hipStream_t stream) {
    const float* values  = (const float*)d_in[0];
    const float* keys    = (const float*)d_in[1];
    const float* queries = (const float*)d_in[2];
    const float* Wk = (const float*)d_in[3];
    const float* Wq = (const float*)d_in[4];
    const float* Wv = (const float*)d_in[5];
    float* out = (float*)d_out;

    unsigned short* Wt2 = (unsigned short*)d_ws;       // 196608 ushorts
    unsigned short* Qb = Wt2 + 196608;                 // Q,K,VT: 3x1048576 ushorts
    unsigned short* Kb = Qb + 1048576;
    unsigned short* VT = Kb + 1048576;

    wt_kernel<<<768, 256, 0, stream>>>(Wq, Wk, Wv, Wt2);
    proj_kernel<<<3072, 256, 0, stream>>>(values, keys, queries, Wt2, Qb, Kb, VT);
    attn_kernel<<<1024, 256, 0, stream>>>(Qb, Kb, VT, out);
}

// Round 12
// 98.337 us; speedup vs baseline: 1.4511x; 1.1674x over previous
//
#include <hip/hip_runtime.h>
#include <hip/hip_bf16.h>

typedef __bf16 bf16x8 __attribute__((ext_vector_type(8)));
typedef float f32x4 __attribute__((ext_vector_type(4)));
typedef unsigned short u16x8 __attribute__((ext_vector_type(8)));

#define NB 8
#define NT 2048
#define NC 1024
#define NH 64

__device__ __forceinline__ unsigned short bfbits(float f) {
    return __builtin_bit_cast(unsigned short, (__bf16)f);
}

// ---------------- kernel 1: W -> W^T (bf16) ----------------
// Wt layout: [3][64][1024], order 0=Wq, 1=Wk, 2=Wv
__global__ __launch_bounds__(256) void wt_kernel(const float* __restrict__ Wq,
                                                 const float* __restrict__ Wk,
                                                 const float* __restrict__ Wv,
                                                 unsigned short* __restrict__ Wt) {
    int idx = blockIdx.x * 256 + threadIdx.x;
    int n = idx >> 16;
    int r = idx & 65535;
    int c = r >> 6;
    int h = r & 63;
    const float* W = (n == 0) ? Wq : ((n == 1) ? Wk : Wv);
    float x = W[c * 64 + h];
    Wt[(n << 16) + h * 1024 + c] = bfbits(x);
}

// ---------------- kernel 2: LDS-staged tiled QKV projection (R4 + NT loads) ----------------
__global__ __launch_bounds__(256, 4) void proj_kernel(const float* __restrict__ Xv,
                                                      const float* __restrict__ Xk,
                                                      const float* __restrict__ Xq,
                                                      const unsigned short* __restrict__ Wt,
                                                      unsigned short* __restrict__ Q,
                                                      unsigned short* __restrict__ K,
                                                      unsigned short* __restrict__ VT) {
    __shared__ __align__(16) char Xs[64 * 256];   // 64 rows x 128 bf16
    __shared__ __align__(16) char Ws[64 * 256];

    int type = blockIdx.x >> 8;          // 0=Q,1=K,2=V
    int mt   = blockIdx.x & 255;
    int row0 = mt << 6;
    const float* X = (type == 0) ? Xq : ((type == 1) ? Xk : Xv);
    const unsigned short* W = Wt + (type << 16);

    int tid  = threadIdx.x;
    int w    = tid >> 6;
    int lane = tid & 63;
    int lo = lane & 15, hi = lane >> 4;

    f32x4 acc[4];
#pragma unroll
    for (int ct = 0; ct < 4; ++ct) acc[ct] = 0.f;

    for (int kc = 0; kc < 8; ++kc) {
        // ---- issue stage loads (X stream = non-temporal) ----
        f32x4 xr[8];
#pragma unroll
        for (int i = 0; i < 8; ++i) {
            int f4 = tid + 256 * i;
            int r  = f4 >> 5, c4 = f4 & 31;
            xr[i] = __builtin_nontemporal_load(
                (const f32x4*)(X + (size_t)(row0 + r) * NC + kc * 128 + c4 * 4));
        }
        u16x8 wr_[4];
#pragma unroll
        for (int i = 0; i < 4; ++i) {
            int s16 = tid + 256 * i;
            int h = s16 >> 4, sl = s16 & 15;
            wr_[i] = *(const u16x8*)(W + h * 1024 + kc * 128 + sl * 8);
        }
        __syncthreads();
#pragma unroll
        for (int i = 0; i < 8; ++i) {
            int f4 = tid + 256 * i;
            int r  = f4 >> 5, c4 = f4 & 31;
            ushort4 bv;
            bv.x = bfbits(xr[i][0]); bv.y = bfbits(xr[i][1]);
            bv.z = bfbits(xr[i][2]); bv.w = bfbits(xr[i][3]);
            int byte = r * 256 + ((c4 * 8) ^ ((r & 7) << 4));
            *(ushort4*)(Xs + byte) = bv;
        }
#pragma unroll
        for (int i = 0; i < 4; ++i) {
            int s16 = tid + 256 * i;
            int h = s16 >> 4, sl = s16 & 15;
            int byte = h * 256 + ((sl * 16) ^ ((h & 7) << 4));
            *(u16x8*)(Ws + byte) = wr_[i];
        }
        __syncthreads();
#pragma unroll
        for (int ks = 0; ks < 4; ++ks) {
            int coff = (ks * 64 + hi * 16) ^ ((lo & 7) << 4);
            bf16x8 af = *(const bf16x8*)(Xs + (w * 16 + lo) * 256 + coff);
#pragma unroll
            for (int ct = 0; ct < 4; ++ct) {
                bf16x8 bf = *(const bf16x8*)(Ws + (ct * 16 + lo) * 256 + coff);
                acc[ct] = __builtin_amdgcn_mfma_f32_16x16x32_bf16(af, bf, acc[ct], 0, 0, 0);
            }
        }
    }

    if (type < 2) {
        unsigned short* O = (type == 0) ? Q : K;
#pragma unroll
        for (int ct = 0; ct < 4; ++ct)
#pragma unroll
            for (int r = 0; r < 4; ++r) {
                int row = row0 + w * 16 + hi * 4 + r;
                int h = lo + 16 * ct;
                O[(size_t)row * NH + h] = bfbits(acc[ct][r]);
            }
    } else {
        int trow = row0 + w * 16 + hi * 4;
        int b = trow >> 11;
        int t = trow & 2047;
#pragma unroll
        for (int ct = 0; ct < 4; ++ct) {
            int h = lo + 16 * ct;
            ushort4 pk;
            pk.x = bfbits(acc[ct][0]);
            pk.y = bfbits(acc[ct][1]);
            pk.z = bfbits(acc[ct][2]);
            pk.w = bfbits(acc[ct][3]);
            *(ushort4*)(VT + (size_t)(b * NH + h) * NT + t) = pk;
        }
    }
}

// ---------------- kernel 3: causal flash attention (optimized) ----------------
// block = 4 waves, one 16-row Q-tile, 4-way s-split + LDS merge.
// Q pre-scaled by SC; full-chunk fast path (no predication below diagonal);
// defer-max (THR=8, exp2 domain); V prefetch; setprio around MFMA; swizzled P-LDS.
__global__ __launch_bounds__(256) void attn_kernel(const unsigned short* __restrict__ Q,
                                                   const unsigned short* __restrict__ K,
                                                   const unsigned short* __restrict__ VT,
                                                   float* __restrict__ out) {
    __shared__ __align__(16) unsigned short p_lds[4 * 512];
    __shared__ __align__(16) float acc_lds[4 * 16 * 64];
    __shared__ float m_lds[4][16];
    __shared__ float l_lds[4][16];

    int b  = blockIdx.x >> 7;
    int qt = blockIdx.x & 127;
    int q0 = qt << 4;
    int w    = threadIdx.x >> 6;
    int lane = threadIdx.x & 63;
    int lo = lane & 15, hi = lane >> 4;

    const float SC = 0.03125f * 1.44269504088896340736f;  // C^-0.5 * log2(e)
    const unsigned short* qb = Q + (size_t)(b * NT + q0 + lo) * NH + hi * 8;
    bf16x8 qr0 = *(const bf16x8*)(qb);
    bf16x8 qr1 = *(const bf16x8*)(qb + 32);
    bf16x8 qf0, qf1;
#pragma unroll
    for (int j = 0; j < 8; ++j) {
        qf0[j] = (__bf16)((float)qr0[j] * SC);
        qf1[j] = (__bf16)((float)qr1[j] * SC);
    }

    int Ctot = (q0 + 16 + 31) >> 5;
    int c0 = (Ctot * w) >> 2;
    int c1 = (Ctot * (w + 1)) >> 2;

    float m[4], l[4];
    f32x4 acc[4];
#pragma unroll
    for (int r = 0; r < 4; ++r) { m[r] = -1e30f; l[r] = 0.f; }
#pragma unroll
    for (int ct = 0; ct < 4; ++ct) acc[ct] = 0.f;

    unsigned short* pl = p_lds + w * 512;
    int g0 = lo >> 3;

    for (int c = c0; c < c1; ++c) {
        int s0 = c << 5;
        const unsigned short* kb = K + (size_t)(b * NT + s0 + lo) * NH + hi * 8;
        f32x4 S0 = 0.f, S1 = 0.f;
        __builtin_amdgcn_s_setprio(1);
        S0 = __builtin_amdgcn_mfma_f32_16x16x32_bf16(qf0, *(const bf16x8*)(kb), S0, 0, 0, 0);
        S0 = __builtin_amdgcn_mfma_f32_16x16x32_bf16(qf1, *(const bf16x8*)(kb + 32), S0, 0, 0, 0);
        S1 = __builtin_amdgcn_mfma_f32_16x16x32_bf16(qf0, *(const bf16x8*)(kb + 16 * NH), S1, 0, 0, 0);
        S1 = __builtin_amdgcn_mfma_f32_16x16x32_bf16(qf1, *(const bf16x8*)(kb + 16 * NH + 32), S1, 0, 0, 0);
        __builtin_amdgcn_s_setprio(0);

        // prefetch V fragments (independent of softmax)
        const unsigned short* vb = VT + (size_t)(b * NH + lo) * NT + s0 + hi * 8;
        bf16x8 vv0 = *(const bf16x8*)(vb);
        bf16x8 vv1 = *(const bf16x8*)(vb + 16 * NT);
        bf16x8 vv2 = *(const bf16x8*)(vb + 32 * NT);
        bf16x8 vv3 = *(const bf16x8*)(vb + 48 * NT);

        bool full = (s0 + 31 <= q0);           // wave-uniform
        float z0[4], z1[4], mt_[4];
        if (full) {
#pragma unroll
            for (int r = 0; r < 4; ++r) {
                z0[r] = S0[r]; z1[r] = S1[r];
                mt_[r] = fmaxf(z0[r], z1[r]);
            }
        } else {
            int s_a = s0 + lo, s_b = s0 + 16 + lo;
#pragma unroll
            for (int r = 0; r < 4; ++r) {
                int qi = q0 + hi * 4 + r;
                z0[r] = (s_a <= qi) ? S0[r] : -1e30f;
                z1[r] = (s_b <= qi) ? S1[r] : -1e30f;
                mt_[r] = fmaxf(z0[r], z1[r]);
            }
        }
#pragma unroll
        for (int d = 1; d < 16; d <<= 1)
#pragma unroll
            for (int r = 0; r < 4; ++r)
                mt_[r] = fmaxf(mt_[r], __shfl_xor(mt_[r], d, 16));

        float p0[4], p1[4], rs[4];
        int small_ = (mt_[0] <= m[0] + 8.f) && (mt_[1] <= m[1] + 8.f) &&
                     (mt_[2] <= m[2] + 8.f) && (mt_[3] <= m[3] + 8.f);
        if (__all(small_)) {
            // defer: keep stale max, no rescale (p bounded by 2^8)
            if (full) {
#pragma unroll
                for (int r = 0; r < 4; ++r) {
                    p0[r] = exp2f(z0[r] - m[r]);
                    p1[r] = exp2f(z1[r] - m[r]);
                    rs[r] = p0[r] + p1[r];
                }
            } else {
                int s_a = s0 + lo, s_b = s0 + 16 + lo;
#pragma unroll
                for (int r = 0; r < 4; ++r) {
                    int qi = q0 + hi * 4 + r;
                    p0[r] = (s_a <= qi) ? exp2f(z0[r] - m[r]) : 0.f;
                    p1[r] = (s_b <= qi) ? exp2f(z1[r] - m[r]) : 0.f;
                    rs[r] = p0[r] + p1[r];
                }
            }
        } else {
            if (full) {
#pragma unroll
                for (int r = 0; r < 4; ++r) {
                    float mn = fmaxf(m[r], mt_[r]);
                    float al = exp2f(m[r] - mn);
                    p0[r] = exp2f(z0[r] - mn);
                    p1[r] = exp2f(z1[r] - mn);
                    rs[r] = p0[r] + p1[r];
                    m[r] = mn; l[r] *= al;
                    acc[0][r] *= al; acc[1][r] *= al; acc[2][r] *= al; acc[3][r] *= al;
                }
            } else {
                int s_a = s0 + lo, s_b = s0 + 16 + lo;
#pragma unroll
                for (int r = 0; r < 4; ++r) {
                    float mn = fmaxf(m[r], mt_[r]);
                    float al = exp2f(m[r] - mn);
                    int qi = q0 + hi * 4 + r;
                    p0[r] = (s_a <= qi) ? exp2f(z0[r] - mn) : 0.f;
                    p1[r] = (s_b <= qi) ? exp2f(z1[r] - mn) : 0.f;
                    rs[r] = p0[r] + p1[r];
                    m[r] = mn; l[r] *= al;
                    acc[0][r] *= al; acc[1][r] *= al; acc[2][r] *= al; acc[3][r] *= al;
                }
            }
        }
#pragma unroll
        for (int d = 1; d < 16; d <<= 1)
#pragma unroll
            for (int r = 0; r < 4; ++r)
                rs[r] += __shfl_xor(rs[r], d, 16);

#pragma unroll
        for (int r = 0; r < 4; ++r) {
            l[r] += rs[r];
            int ql = hi * 4 + r;    // ql & 3 == r
            pl[ql * 32 + (((g0 ^ r) << 3) | (lo & 7))]        = bfbits(p0[r]);
            pl[ql * 32 + ((((g0 | 2) ^ r) << 3) | (lo & 7))]  = bfbits(p1[r]);
        }
        // P transpose read (swizzled, wave-private -> compiler inserts lgkmcnt)
        bf16x8 pa = *(const bf16x8*)(pl + lo * 32 + ((hi ^ (lo & 3)) << 3));
        __builtin_amdgcn_s_setprio(1);
        acc[0] = __builtin_amdgcn_mfma_f32_16x16x32_bf16(pa, vv0, acc[0], 0, 0, 0);
        acc[1] = __builtin_amdgcn_mfma_f32_16x16x32_bf16(pa, vv1, acc[1], 0, 0, 0);
        acc[2] = __builtin_amdgcn_mfma_f32_16x16x32_bf16(pa, vv2, acc[2], 0, 0, 0);
        acc[3] = __builtin_amdgcn_mfma_f32_16x16x32_bf16(pa, vv3, acc[3], 0, 0, 0);
        __builtin_amdgcn_s_setprio(0);
    }

    // dump per-wave partial state
#pragma unroll
    for (int r = 0; r < 4; ++r) {
        int ql = hi * 4 + r;
#pragma unroll
        for (int ct = 0; ct < 4; ++ct)
            acc_lds[(w * 16 + ql) * 64 + lo + 16 * ct] = acc[ct][r];
    }
    if (lo == 0) {
#pragma unroll
        for (int r = 0; r < 4; ++r) {
            m_lds[w][hi * 4 + r] = m[r];
            l_lds[w][hi * 4 + r] = l[r];
        }
    }
    __syncthreads();

    // merge 4 s-splits
    int q  = threadIdx.x >> 4;
    int h0 = (threadIdx.x & 15) << 2;
    float M = fmaxf(fmaxf(m_lds[0][q], m_lds[1][q]), fmaxf(m_lds[2][q], m_lds[3][q]));
    float L = 0.f;
    float ox = 0.f, oy = 0.f, oz = 0.f, ow = 0.f;
#pragma unroll
    for (int ww = 0; ww < 4; ++ww) {
        float a_ = exp2f(m_lds[ww][q] - M);
        L += a_ * l_lds[ww][q];
        const float* p = acc_lds + (ww * 16 + q) * 64 + h0;
        ox += a_ * p[0]; oy += a_ * p[1]; oz += a_ * p[2]; ow += a_ * p[3];
    }
    float inv = 1.0f / L;
    float4 res = make_float4(ox * inv, oy * inv, oz * inv, ow * inv);
    *(float4*)(out + (size_t)(b * NT + q0 + q) * NH + h0) = res;
}

extern "C" void kernel_launch(void* const* d_in, const int* in_sizes, int n_in,
                              void* d_out, int out_size, void* d_ws, size_t ws_size,
                              hipStream_t stream) {
    const float* values  = (const float*)d_in[0];
    const float* keys    = (const float*)d_in[1];
    const float* queries = (const float*)d_in[2];
    const float* Wk = (const float*)d_in[3];
    const float* Wq = (const float*)d_in[4];
    const float* Wv = (const float*)d_in[5];
    float* out = (float*)d_out;

    unsigned short* Wt = (unsigned short*)d_ws;        // 196608 ushorts
    unsigned short* Qb = Wt + 196608;                  // Q,K,VT: 3x1048576 ushorts
    unsigned short* Kb = Qb + 1048576;
    unsigned short* VT = Kb + 1048576;

    wt_kernel<<<768, 256, 0, stream>>>(Wq, Wk, Wv, Wt);
    proj_kernel<<<768, 256, 0, stream>>>(values, keys, queries, Wt, Qb, Kb, VT);
    attn_kernel<<<1024, 256, 0, stream>>>(Qb, Kb, VT, out);
}